// Round 1
// baseline (303.702 us; speedup 1.0000x reference)
//
#include <hip/hip_runtime.h>
#include <math.h>

#define NQ 22
#define DIM (1u << NQ)

// ---------------- fused gate matrices: U = RZ * RY * RX, fp64 -> fp32 ----------------
__global__ void k_gates(const float* __restrict__ params, float* __restrict__ U) {
  int t = blockIdx.x * blockDim.x + threadIdx.x;
  if (t >= 88) return;               // t = l*22 + q
  const float* p = params + t * 3;
  double hx = 0.5 * (double)p[0], hy = 0.5 * (double)p[1], hz = 0.5 * (double)p[2];
  double cx = cos(hx), sx = sin(hx);
  double cy = cos(hy), sy = sin(hy);
  double cz = cos(hz), sz = sin(hz);
  // M = RY*RX ; RX=[[cx,-i sx],[-i sx,cx]], RY=[[cy,-sy],[sy,cy]]
  double m00r = cy * cx, m00i = sy * sx;
  double m01r = -sy * cx, m01i = -cy * sx;
  double m10r = sy * cx, m10i = -cy * sx;
  double m11r = cy * cx, m11i = -sy * sx;
  // U = RZ*M : row0 *= (cz - i sz), row1 *= (cz + i sz)
  float* o = U + t * 8;
  o[0] = (float)(cz * m00r + sz * m00i); o[1] = (float)(cz * m00i - sz * m00r);
  o[2] = (float)(cz * m01r + sz * m01i); o[3] = (float)(cz * m01i - sz * m01r);
  o[4] = (float)(cz * m10r - sz * m10i); o[5] = (float)(cz * m10i + sz * m10r);
  o[6] = (float)(cz * m11r - sz * m11i); o[7] = (float)(cz * m11i + sz * m11r);
}

// ---------------- gate application helpers ----------------
__device__ __forceinline__ void cgate(float2& a0, float2& a1,
                                      float u0, float u1, float u2, float u3,
                                      float u4, float u5, float u6, float u7) {
  float n0r = u0 * a0.x - u1 * a0.y + u2 * a1.x - u3 * a1.y;
  float n0i = u0 * a0.y + u1 * a0.x + u2 * a1.y + u3 * a1.x;
  float n1r = u4 * a0.x - u5 * a0.y + u6 * a1.x - u7 * a1.y;
  float n1i = u4 * a0.y + u5 * a0.x + u6 * a1.y + u7 * a1.x;
  a0.x = n0r; a0.y = n0i; a1.x = n1r; a1.y = n1i;
}

template <int B>
__device__ __forceinline__ void apply_bit(float2 v[16], const float* __restrict__ u) {
  float u0 = u[0], u1 = u[1], u2 = u[2], u3 = u[3], u4 = u[4], u5 = u[5], u6 = u[6], u7 = u[7];
#pragma unroll
  for (int m = 0; m < 8; ++m) {
    int d0 = ((m >> B) << (B + 1)) | (m & ((1 << B) - 1));
    int d1 = d0 | (1 << B);
    cgate(v[d0], v[d1], u0, u1, u2, u3, u4, u5, u6, u7);
  }
}

// d-bit b uses wire (wtop - b); U entry stride 8 floats
__device__ __forceinline__ void apply4(float2 v[16], const float* __restrict__ U,
                                       int l, int wtop, int nb) {
  const float* base = U + ((l * 22 + wtop) << 3);
  apply_bit<0>(v, base);
  if (nb > 1) apply_bit<1>(v, base - 8);
  if (nb > 2) apply_bit<2>(v, base - 16);
  if (nb > 3) apply_bit<3>(v, base - 24);
}

// LDS exchange: single float array, re then im (halves LDS footprint)
template <typename WI, typename RI>
__device__ __forceinline__ void xchg(float* lds, float2 v[16], WI wi, RI ri) {
  float tmp[16];
  __syncthreads();
#pragma unroll
  for (int d = 0; d < 16; ++d) lds[wi(d)] = v[d].x;
  __syncthreads();
#pragma unroll
  for (int d = 0; d < 16; ++d) tmp[d] = lds[ri(d)];
  __syncthreads();
#pragma unroll
  for (int d = 0; d < 16; ++d) lds[wi(d)] = v[d].y;
  __syncthreads();
#pragma unroll
  for (int d = 0; d < 16; ++d) { v[d].x = tmp[d]; v[d].y = lds[ri(d)]; }
}

// ---------------- pass A: gates on bits 0..11 (wires 21..10) ----------------
// block = 4096 contiguous amps, 256 threads x 16 amps. Gray-gather on load (layers>=1)
__global__ __launch_bounds__(256) void k_passA(const float* __restrict__ srcRe,
                                               const float* __restrict__ srcIm,
                                               const float2* __restrict__ src2,
                                               float2* __restrict__ dst,
                                               const float* __restrict__ U,
                                               int layer, int first) {
  __shared__ float lds[4352];  // swizzle idx j + (j>>4): max 4095+255=4350
  const int t = threadIdx.x;
  const unsigned base = ((unsigned)blockIdx.x << 12) | ((unsigned)t << 4);
  float2 v[16];
  if (first) {
    const float4* r4 = (const float4*)(srcRe + base);
    const float4* i4 = (const float4*)(srcIm + base);
#pragma unroll
    for (int k = 0; k < 4; ++k) {
      float4 r = r4[k], m = i4[k];
      v[4 * k + 0] = make_float2(r.x, m.x);
      v[4 * k + 1] = make_float2(r.y, m.y);
      v[4 * k + 2] = make_float2(r.z, m.z);
      v[4 * k + 3] = make_float2(r.w, m.w);
    }
  } else {
#pragma unroll
    for (int d = 0; d < 16; ++d) {
      unsigned j = base + d;
      v[d] = src2[j ^ (j >> 1)];   // fused CNOT-chain permutation of previous layer
    }
  }
  apply4(v, U, layer, 21, 4);      // global bits 0..3  -> wires 21..18
  xchg(lds, v,
       [&](int d) { unsigned j = ((unsigned)t << 4) | (unsigned)d; return j + (j >> 4); },
       [&](int d) { unsigned j = (((unsigned)t >> 4) << 8) | ((unsigned)d << 4) | ((unsigned)t & 15); return j + (j >> 4); });
  apply4(v, U, layer, 17, 4);      // bits 4..7 -> wires 17..14
  xchg(lds, v,
       [&](int d) { unsigned j = (((unsigned)t >> 4) << 8) | ((unsigned)d << 4) | ((unsigned)t & 15); return j + (j >> 4); },
       [&](int d) { unsigned j = ((unsigned)d << 8) | (unsigned)t; return j + (j >> 4); });
  apply4(v, U, layer, 13, 4);      // bits 8..11 -> wires 13..10
  xchg(lds, v,
       [&](int d) { unsigned j = ((unsigned)d << 8) | (unsigned)t; return j + (j >> 4); },
       [&](int d) { unsigned j = ((unsigned)t << 4) | (unsigned)d; return j + (j >> 4); });
  float4* o4 = (float4*)(dst + base);
#pragma unroll
  for (int k = 0; k < 8; ++k)
    o4[k] = make_float4(v[2 * k].x, v[2 * k].y, v[2 * k + 1].x, v[2 * k + 1].y);
}

// ---------------- pass B: gates on bits 12..21 (wires 9..0) ----------------
// block = 1024 h-rows (bits 12..21) x 8 columns (bits 0..2), bits 3..11 = blockIdx
__global__ __launch_bounds__(512) void k_passB(const float2* __restrict__ src,
                                               float2* __restrict__ dst,
                                               const float* __restrict__ U,
                                               int layer) {
  __shared__ float lds[9216];   // idx = h*9 + c
  const int t = threadIdx.x;
  const int c = t & 7, u = t >> 3;   // u in 0..63
  const unsigned lowbase = ((unsigned)blockIdx.x << 3) | (unsigned)c;
  float2 v[16];
  // M0': h = u | (d<<6) -> d at h-bits 6..9 = global 18..21 (wires 3..0)
#pragma unroll
  for (int d = 0; d < 16; ++d) {
    unsigned h = (unsigned)u | ((unsigned)d << 6);
    v[d] = src[(h << 12) | lowbase];
  }
  apply4(v, U, layer, 3, 4);
  // X1 -> M1': h = (u&3) | (d<<2) | ((u>>2)<<6): d = global 14..17 (wires 7..4)
  xchg(lds, v,
       [&](int d) { unsigned h = (unsigned)u | ((unsigned)d << 6); return h * 9u + (unsigned)c; },
       [&](int d) { unsigned h = ((unsigned)u & 3u) | ((unsigned)d << 2) | (((unsigned)u >> 2) << 6); return h * 9u + (unsigned)c; });
  apply4(v, U, layer, 7, 4);
  // X2 -> M2'': h = (d&3) | (u<<2) | ((d>>2)<<8): d-bits 0,1 = global 12,13 (wires 9,8)
  xchg(lds, v,
       [&](int d) { unsigned h = ((unsigned)u & 3u) | ((unsigned)d << 2) | (((unsigned)u >> 2) << 6); return h * 9u + (unsigned)c; },
       [&](int d) { unsigned h = ((unsigned)d & 3u) | ((unsigned)u << 2) | (((unsigned)d >> 2) << 8); return h * 9u + (unsigned)c; });
  apply4(v, U, layer, 9, 2);
#pragma unroll
  for (int d = 0; d < 16; ++d) {
    unsigned h = ((unsigned)d & 3u) | ((unsigned)u << 2) | (((unsigned)d >> 2) << 8);
    dst[(h << 12) | lowbase] = v[d];
  }
}

// ---------------- expvals with fused final CNOT chain (sign trick) ----------------
__global__ __launch_bounds__(256) void k_expval(const float2* __restrict__ src,
                                                float* __restrict__ partials) {
  const int t = threadIdx.x, b = blockIdx.x;
  const float4* s4 = (const float4*)src;
  float acc[22];
#pragma unroll
  for (int q = 0; q < 22; ++q) acc[q] = 0.f;
  float tot = 0.f;
#pragma unroll 2
  for (int k = 0; k < 32; ++k) {
    unsigned idx4 = ((unsigned)b << 13) | ((unsigned)k << 8) | (unsigned)t;
    float4 w = s4[idx4];
    unsigned x = idx4 << 1;                       // amp index (even half of pair)
    x ^= x >> 1; x ^= x >> 2; x ^= x >> 4; x ^= x >> 8; x ^= x >> 16;  // inverse Gray
    float p0 = w.x * w.x + w.y * w.y;
    float p1 = w.z * w.z + w.w * w.w;
    float ps = p0 + p1, pd = p0 - p1;
    tot += ps;
#pragma unroll
    for (int q = 0; q < 21; ++q)
      acc[q] += ((x >> (21 - q)) & 1u) ? -ps : ps;
    acc[21] += (x & 1u) ? -pd : pd;               // odd amp flips only bit 0 of x
  }
  __shared__ float red[4 * 23];
  const int lane = t & 63, wv = t >> 6;
#pragma unroll
  for (int q = 0; q < 22; ++q) {
    float s = acc[q];
    for (int off = 32; off > 0; off >>= 1) s += __shfl_down(s, off, 64);
    if (lane == 0) red[wv * 23 + q] = s;
  }
  {
    float s = tot;
    for (int off = 32; off > 0; off >>= 1) s += __shfl_down(s, off, 64);
    if (lane == 0) red[wv * 23 + 22] = s;
  }
  __syncthreads();
  if (t < 23) partials[t * 256 + b] = red[t] + red[23 + t] + red[46 + t] + red[69 + t];
}

__global__ void k_final(const float* __restrict__ partials, float* __restrict__ out) {
  __shared__ double res[23];
  const int t = threadIdx.x;
  if (t < 23) {
    const float4* p4 = (const float4*)(partials + t * 256);
    double s = 0.0;
    for (int k = 0; k < 64; ++k) {
      float4 v = p4[k];
      s += (double)v.x + (double)v.y + (double)v.z + (double)v.w;
    }
    res[t] = s;
  }
  __syncthreads();
  if (t < 22) out[t] = (float)(res[t] / res[22]);  // normalization folded in here
}

extern "C" void kernel_launch(void* const* d_in, const int* in_sizes, int n_in,
                              void* d_out, int out_size, void* d_ws, size_t ws_size,
                              hipStream_t stream) {
  const float* params = (const float*)d_in[0];   // [4][22][3]
  const float* sre = (const float*)d_in[1];      // [DIM]
  const float* sim = (const float*)d_in[2];      // [DIM]
  float* out = (float*)d_out;                    // [22]
  char* ws = (char*)d_ws;
  float* U = (float*)ws;                         // 88 * 8 floats
  float* partials = (float*)(ws + 4096);         // 23 * 256 floats
  float2* buf0 = (float2*)(ws + 32768);          // 32 MB
  float2* buf1 = buf0 + DIM;                     // 32 MB (needs ws >= ~67 MB)

  k_gates<<<1, 128, 0, stream>>>(params, U);
  // layer 0 (no permutation on input)
  k_passA<<<1024, 256, 0, stream>>>(sre, sim, nullptr, buf0, U, 0, 1);
  k_passB<<<512, 512, 0, stream>>>(buf0, buf1, U, 0);
  for (int l = 1; l < 4; ++l) {
    k_passA<<<1024, 256, 0, stream>>>(nullptr, nullptr, buf1, buf0, U, l, 0);
    k_passB<<<512, 512, 0, stream>>>(buf0, buf1, U, l);
  }
  k_expval<<<256, 256, 0, stream>>>(buf1, partials);
  k_final<<<1, 64, 0, stream>>>(partials, out);
}

// Round 2
// 248.198 us; speedup vs baseline: 1.2236x; 1.2236x over previous
//
#include <hip/hip_runtime.h>
#include <math.h>

#define NQ 22
#define DIM (1u << NQ)

// ---------------- fused gate matrices: U = RZ * RY * RX, fp64 -> fp32 ----------------
__global__ void k_gates(const float* __restrict__ params, float* __restrict__ U) {
  int t = blockIdx.x * blockDim.x + threadIdx.x;
  if (t >= 88) return;               // t = l*22 + q
  const float* p = params + t * 3;
  double hx = 0.5 * (double)p[0], hy = 0.5 * (double)p[1], hz = 0.5 * (double)p[2];
  double cx = cos(hx), sx = sin(hx);
  double cy = cos(hy), sy = sin(hy);
  double cz = cos(hz), sz = sin(hz);
  double m00r = cy * cx, m00i = sy * sx;
  double m01r = -sy * cx, m01i = -cy * sx;
  double m10r = sy * cx, m10i = -cy * sx;
  double m11r = cy * cx, m11i = -sy * sx;
  float* o = U + t * 8;
  o[0] = (float)(cz * m00r + sz * m00i); o[1] = (float)(cz * m00i - sz * m00r);
  o[2] = (float)(cz * m01r + sz * m01i); o[3] = (float)(cz * m01i - sz * m01r);
  o[4] = (float)(cz * m10r - sz * m10i); o[5] = (float)(cz * m10i + sz * m10r);
  o[6] = (float)(cz * m11r - sz * m11i); o[7] = (float)(cz * m11i + sz * m11r);
}

// ---------------- gate application helpers ----------------
__device__ __forceinline__ void cgate(float2& a0, float2& a1,
                                      float u0, float u1, float u2, float u3,
                                      float u4, float u5, float u6, float u7) {
  float n0r = u0 * a0.x - u1 * a0.y + u2 * a1.x - u3 * a1.y;
  float n0i = u0 * a0.y + u1 * a0.x + u2 * a1.y + u3 * a1.x;
  float n1r = u4 * a0.x - u5 * a0.y + u6 * a1.x - u7 * a1.y;
  float n1i = u4 * a0.y + u5 * a0.x + u6 * a1.y + u7 * a1.x;
  a0.x = n0r; a0.y = n0i; a1.x = n1r; a1.y = n1i;
}

template <int B>
__device__ __forceinline__ void apply_bit(float2 v[16], const float* __restrict__ u) {
  float u0 = u[0], u1 = u[1], u2 = u[2], u3 = u[3], u4 = u[4], u5 = u[5], u6 = u[6], u7 = u[7];
#pragma unroll
  for (int m = 0; m < 8; ++m) {
    int d0 = ((m >> B) << (B + 1)) | (m & ((1 << B) - 1));
    int d1 = d0 | (1 << B);
    cgate(v[d0], v[d1], u0, u1, u2, u3, u4, u5, u6, u7);
  }
}

// d-bit b uses wire (wtop - b); U entry stride 8 floats
__device__ __forceinline__ void apply4(float2 v[16], const float* __restrict__ U,
                                       int l, int wtop, int nb) {
  const float* base = U + ((l * 22 + wtop) << 3);
  apply_bit<0>(v, base);
  if (nb > 1) apply_bit<1>(v, base - 8);
  if (nb > 2) apply_bit<2>(v, base - 16);
  if (nb > 3) apply_bit<3>(v, base - 24);
}

// two-plane LDS exchange: re in [0,plane), im in [plane,2*plane). 2 barriers.
template <int PLANE, typename WI, typename RI>
__device__ __forceinline__ void xchg2p(float* lds, float2 v[16], WI wi, RI ri) {
  __syncthreads();
#pragma unroll
  for (int d = 0; d < 16; ++d) { int e = wi(d); lds[e] = v[d].x; lds[PLANE + e] = v[d].y; }
  __syncthreads();
#pragma unroll
  for (int d = 0; d < 16; ++d) { int e = ri(d); v[d].x = lds[e]; v[d].y = lds[PLANE + e]; }
}

// single-plane exchange (re then im), 4 barriers — for 64 KB-bound kernels
template <typename WI, typename RI>
__device__ __forceinline__ void xchg1p(float* lds, float2 v[16], WI wi, RI ri) {
  float tmp[16];
  __syncthreads();
#pragma unroll
  for (int d = 0; d < 16; ++d) lds[wi(d)] = v[d].x;
  __syncthreads();
#pragma unroll
  for (int d = 0; d < 16; ++d) tmp[d] = lds[ri(d)];
  __syncthreads();
#pragma unroll
  for (int d = 0; d < 16; ++d) lds[wi(d)] = v[d].y;
  __syncthreads();
#pragma unroll
  for (int d = 0; d < 16; ++d) { v[d].x = tmp[d]; v[d].y = lds[ri(d)]; }
}

// ---------------- pass A: gates on bits 0..11 (wires 21..10) ----------------
// block = 4096 contiguous amps, 256 threads x 16 amps.
// Gray-gather (layers>=1) done as coalesced window load + register permute:
//   G(b*16+d) = ((b^(b>>1))<<4) | ((d^(d>>1)) ^ ((b&1)<<3))
#define PA_PLANE 4352
__global__ __launch_bounds__(256) void k_passA(const float* __restrict__ srcRe,
                                               const float* __restrict__ srcIm,
                                               const float2* __restrict__ src2,
                                               float2* __restrict__ dst,
                                               const float* __restrict__ U,
                                               int layer, int first) {
  __shared__ float lds[2 * PA_PLANE];  // swizzle idx j + (j>>4): max 4095+255=4350
  const int t = threadIdx.x;
  const unsigned base = ((unsigned)blockIdx.x << 12) | ((unsigned)t << 4);
  float2 v[16];
  if (first) {
    const float4* r4 = (const float4*)(srcRe + base);
    const float4* i4 = (const float4*)(srcIm + base);
#pragma unroll
    for (int k = 0; k < 4; ++k) {
      float4 r = r4[k], m = i4[k];
      v[4 * k + 0] = make_float2(r.x, m.x);
      v[4 * k + 1] = make_float2(r.y, m.y);
      v[4 * k + 2] = make_float2(r.z, m.z);
      v[4 * k + 3] = make_float2(r.w, m.w);
    }
  } else {
    const unsigned b = base >> 4;
    const unsigned W = (b ^ (b >> 1)) << 4;   // aligned 16-amp window
    const float4* s4 = (const float4*)(src2 + W);
    float2 w2[16];
#pragma unroll
    for (int k = 0; k < 8; ++k) {
      float4 x = s4[k];
      w2[2 * k] = make_float2(x.x, x.y);
      w2[2 * k + 1] = make_float2(x.z, x.w);
    }
    if (b & 1) {                               // flip bit 3 of window offset
#pragma unroll
      for (int k = 0; k < 8; ++k) { float2 tt = w2[k]; w2[k] = w2[k + 8]; w2[k + 8] = tt; }
    }
#pragma unroll
    for (int d = 0; d < 16; ++d) v[d] = w2[d ^ (d >> 1)];  // compile-time indices
  }
  apply4(v, U, layer, 21, 4);      // global bits 0..3  -> wires 21..18
  xchg2p<PA_PLANE>(lds, v,
       [&](int d) { unsigned j = ((unsigned)t << 4) | (unsigned)d; return (int)(j + (j >> 4)); },
       [&](int d) { unsigned j = (((unsigned)t >> 4) << 8) | ((unsigned)d << 4) | ((unsigned)t & 15); return (int)(j + (j >> 4)); });
  apply4(v, U, layer, 17, 4);      // bits 4..7 -> wires 17..14
  xchg2p<PA_PLANE>(lds, v,
       [&](int d) { unsigned j = (((unsigned)t >> 4) << 8) | ((unsigned)d << 4) | ((unsigned)t & 15); return (int)(j + (j >> 4)); },
       [&](int d) { unsigned j = ((unsigned)d << 8) | (unsigned)t; return (int)(j + (j >> 4)); });
  apply4(v, U, layer, 13, 4);      // bits 8..11 -> wires 13..10
  xchg2p<PA_PLANE>(lds, v,
       [&](int d) { unsigned j = ((unsigned)d << 8) | (unsigned)t; return (int)(j + (j >> 4)); },
       [&](int d) { unsigned j = ((unsigned)t << 4) | (unsigned)d; return (int)(j + (j >> 4)); });
  float4* o4 = (float4*)(dst + base);
#pragma unroll
  for (int k = 0; k < 8; ++k)
    o4[k] = make_float4(v[2 * k].x, v[2 * k].y, v[2 * k + 1].x, v[2 * k + 1].y);
}

// ---------------- pass B: gates on bits 12..21 (wires 9..0) ----------------
// block = 1024 h-rows (bits 12..21) x 16 columns (bits 0..3), bits 4..11 = blockIdx
// 1024 threads x 16 amps. All global segments = 16 cols x 8 B = 128 B.
__global__ __launch_bounds__(1024) void k_passB(const float2* __restrict__ src,
                                                float2* __restrict__ dst,
                                                const float* __restrict__ U,
                                                int layer) {
  __shared__ float lds[16384];   // exactly 64 KB; e = (h<<4) | (c ^ (h&15)) XOR swizzle
  const int t = threadIdx.x;
  const int c = t & 15, u = t >> 4;   // u in 0..63
  const unsigned lowbase = ((unsigned)blockIdx.x << 4) | (unsigned)c;
  float2 v[16];
#pragma unroll
  for (int d = 0; d < 16; ++d) {
    unsigned h = (unsigned)u | ((unsigned)d << 6);   // d at h-bits 6..9 (wires 3..0)
    v[d] = src[(h << 12) | lowbase];
  }
  apply4(v, U, layer, 3, 4);
  // X1: h = (u&3) | (d<<2) | ((u>>2)<<6): d = global 14..17 (wires 7..4)
  xchg1p(lds, v,
       [&](int d) { unsigned h = (unsigned)u | ((unsigned)d << 6); return (int)((h << 4) | ((unsigned)c ^ (h & 15u))); },
       [&](int d) { unsigned h = ((unsigned)u & 3u) | ((unsigned)d << 2) | (((unsigned)u >> 2) << 6); return (int)((h << 4) | ((unsigned)c ^ (h & 15u))); });
  apply4(v, U, layer, 7, 4);
  // X2: h = (d&3) | (u<<2) | ((d>>2)<<8): d-bits 0,1 = global 12,13 (wires 9,8)
  xchg1p(lds, v,
       [&](int d) { unsigned h = ((unsigned)u & 3u) | ((unsigned)d << 2) | (((unsigned)u >> 2) << 6); return (int)((h << 4) | ((unsigned)c ^ (h & 15u))); },
       [&](int d) { unsigned h = ((unsigned)d & 3u) | ((unsigned)u << 2) | (((unsigned)d >> 2) << 8); return (int)((h << 4) | ((unsigned)c ^ (h & 15u))); });
  apply4(v, U, layer, 9, 2);
#pragma unroll
  for (int d = 0; d < 16; ++d) {
    unsigned h = ((unsigned)d & 3u) | ((unsigned)u << 2) | (((unsigned)d >> 2) << 8);
    dst[(h << 12) | lowbase] = v[d];
  }
}

// ---------------- expvals with fused final CNOT chain (sign trick) ----------------
#define EV_BLOCKS 1024
__global__ __launch_bounds__(256) void k_expval(const float2* __restrict__ src,
                                                float* __restrict__ partials) {
  const int t = threadIdx.x, b = blockIdx.x;
  const float4* s4 = (const float4*)src;
  float acc[22];
#pragma unroll
  for (int q = 0; q < 22; ++q) acc[q] = 0.f;
  float tot = 0.f;
#pragma unroll
  for (int k = 0; k < 8; ++k) {
    unsigned idx4 = ((unsigned)b << 11) | ((unsigned)k << 8) | (unsigned)t;
    float4 w = s4[idx4];
    unsigned x = idx4 << 1;                       // amp index (even half of pair)
    x ^= x >> 1; x ^= x >> 2; x ^= x >> 4; x ^= x >> 8; x ^= x >> 16;  // inverse Gray
    float p0 = w.x * w.x + w.y * w.y;
    float p1 = w.z * w.z + w.w * w.w;
    float ps = p0 + p1, pd = p0 - p1;
    tot += ps;
#pragma unroll
    for (int q = 0; q < 21; ++q)
      acc[q] += ((x >> (21 - q)) & 1u) ? -ps : ps;
    acc[21] += (x & 1u) ? -pd : pd;               // odd amp flips only bit 0 of x
  }
  __shared__ float red[4 * 23];
  const int lane = t & 63, wv = t >> 6;
#pragma unroll
  for (int q = 0; q < 22; ++q) {
    float s = acc[q];
    for (int off = 32; off > 0; off >>= 1) s += __shfl_down(s, off, 64);
    if (lane == 0) red[wv * 23 + q] = s;
  }
  {
    float s = tot;
    for (int off = 32; off > 0; off >>= 1) s += __shfl_down(s, off, 64);
    if (lane == 0) red[wv * 23 + 22] = s;
  }
  __syncthreads();
  if (t < 23) partials[t * EV_BLOCKS + b] = red[t] + red[23 + t] + red[46 + t] + red[69 + t];
}

__global__ void k_final(const float* __restrict__ partials, float* __restrict__ out) {
  __shared__ double res[24];
  const int t = threadIdx.x;
  const int r = t >> 3, l8 = t & 7;
  if (r < 23) {
    double s = 0.0;
    const float* p = partials + r * EV_BLOCKS + l8 * 128;
    for (int k = 0; k < 128; ++k) s += (double)p[k];
    for (int off = 4; off > 0; off >>= 1) s += __shfl_down(s, off, 8);
    if (l8 == 0) res[r] = s;
  }
  __syncthreads();
  if (t < 22) out[t] = (float)(res[t] / res[22]);  // normalization folded in here
}

extern "C" void kernel_launch(void* const* d_in, const int* in_sizes, int n_in,
                              void* d_out, int out_size, void* d_ws, size_t ws_size,
                              hipStream_t stream) {
  const float* params = (const float*)d_in[0];   // [4][22][3]
  const float* sre = (const float*)d_in[1];      // [DIM]
  const float* sim = (const float*)d_in[2];      // [DIM]
  float* out = (float*)d_out;                    // [22]
  char* ws = (char*)d_ws;
  float* U = (float*)ws;                         // 88 * 8 floats
  float* partials = (float*)(ws + 4096);         // 23 * 1024 floats (= 94 KB)
  float2* buf0 = (float2*)(ws + 131072);         // 32 MB
  float2* buf1 = buf0 + DIM;                     // 32 MB

  k_gates<<<1, 128, 0, stream>>>(params, U);
  // layer 0 (no permutation on input)
  k_passA<<<1024, 256, 0, stream>>>(sre, sim, nullptr, buf0, U, 0, 1);
  k_passB<<<256, 1024, 0, stream>>>(buf0, buf1, U, 0);
  for (int l = 1; l < 4; ++l) {
    k_passA<<<1024, 256, 0, stream>>>(nullptr, nullptr, buf1, buf0, U, l, 0);
    k_passB<<<256, 1024, 0, stream>>>(buf0, buf1, U, l);
  }
  k_expval<<<EV_BLOCKS, 256, 0, stream>>>(buf1, partials);
  k_final<<<1, 256, 0, stream>>>(partials, out);
}

// Round 3
// 245.389 us; speedup vs baseline: 1.2376x; 1.0114x over previous
//
#include <hip/hip_runtime.h>
#include <math.h>

#define NQ 22
#define DIM (1u << NQ)

// ---------------- fused gate matrices: U = RZ * RY * RX, fp64 -> fp32 ----------------
__global__ void k_gates(const float* __restrict__ params, float* __restrict__ U) {
  int t = blockIdx.x * blockDim.x + threadIdx.x;
  if (t >= 88) return;               // t = l*22 + q
  const float* p = params + t * 3;
  double hx = 0.5 * (double)p[0], hy = 0.5 * (double)p[1], hz = 0.5 * (double)p[2];
  double cx = cos(hx), sx = sin(hx);
  double cy = cos(hy), sy = sin(hy);
  double cz = cos(hz), sz = sin(hz);
  double m00r = cy * cx, m00i = sy * sx;
  double m01r = -sy * cx, m01i = -cy * sx;
  double m10r = sy * cx, m10i = -cy * sx;
  double m11r = cy * cx, m11i = -sy * sx;
  float* o = U + t * 8;
  o[0] = (float)(cz * m00r + sz * m00i); o[1] = (float)(cz * m00i - sz * m00r);
  o[2] = (float)(cz * m01r + sz * m01i); o[3] = (float)(cz * m01i - sz * m01r);
  o[4] = (float)(cz * m10r - sz * m10i); o[5] = (float)(cz * m10i + sz * m10r);
  o[6] = (float)(cz * m11r - sz * m11i); o[7] = (float)(cz * m11i + sz * m11r);
}

// ---------------- gate application helpers ----------------
__device__ __forceinline__ void cgate(float2& a0, float2& a1,
                                      float u0, float u1, float u2, float u3,
                                      float u4, float u5, float u6, float u7) {
  float n0r = u0 * a0.x - u1 * a0.y + u2 * a1.x - u3 * a1.y;
  float n0i = u0 * a0.y + u1 * a0.x + u2 * a1.y + u3 * a1.x;
  float n1r = u4 * a0.x - u5 * a0.y + u6 * a1.x - u7 * a1.y;
  float n1i = u4 * a0.y + u5 * a0.x + u6 * a1.y + u7 * a1.x;
  a0.x = n0r; a0.y = n0i; a1.x = n1r; a1.y = n1i;
}

template <int B>
__device__ __forceinline__ void apply_bit(float2 v[16], const float* __restrict__ u) {
  float u0 = u[0], u1 = u[1], u2 = u[2], u3 = u[3], u4 = u[4], u5 = u[5], u6 = u[6], u7 = u[7];
#pragma unroll
  for (int m = 0; m < 8; ++m) {
    int d0 = ((m >> B) << (B + 1)) | (m & ((1 << B) - 1));
    int d1 = d0 | (1 << B);
    cgate(v[d0], v[d1], u0, u1, u2, u3, u4, u5, u6, u7);
  }
}

// d-bit b uses wire (wtop - b); U entry stride 8 floats
__device__ __forceinline__ void apply4(float2 v[16], const float* __restrict__ U,
                                       int l, int wtop, int nb) {
  const float* base = U + ((l * 22 + wtop) << 3);
  apply_bit<0>(v, base);
  if (nb > 1) apply_bit<1>(v, base - 8);
  if (nb > 2) apply_bit<2>(v, base - 16);
  if (nb > 3) apply_bit<3>(v, base - 24);
}

// two-plane LDS exchange: re in [0,PLANE), im in [PLANE,2*PLANE). 2 barriers.
template <int PLANE, typename WI, typename RI>
__device__ __forceinline__ void xchg2p(float* lds, float2 v[16], WI wi, RI ri) {
  __syncthreads();
#pragma unroll
  for (int d = 0; d < 16; ++d) { int e = wi(d); lds[e] = v[d].x; lds[PLANE + e] = v[d].y; }
  __syncthreads();
#pragma unroll
  for (int d = 0; d < 16; ++d) { int e = ri(d); v[d].x = lds[e]; v[d].y = lds[PLANE + e]; }
}

// ---------------- pass A: gates on bits 0..11 (wires 21..10) ----------------
// block = 4096 contiguous amps, 256 threads x 16 amps.
// Gray-gather (layers>=1) done as coalesced window load + register permute:
//   G(b*16+d) = ((b^(b>>1))<<4) | ((d^(d>>1)) ^ ((b&1)<<3))
#define PA_PLANE 4352
__global__ __launch_bounds__(256, 4) void k_passA(const float* __restrict__ srcRe,
                                                  const float* __restrict__ srcIm,
                                                  const float2* __restrict__ src2,
                                                  float2* __restrict__ dst,
                                                  const float* __restrict__ U,
                                                  int layer, int first) {
  __shared__ float lds[2 * PA_PLANE];  // swizzle idx j + (j>>4): max 4095+255=4350
  const int t = threadIdx.x;
  const unsigned base = ((unsigned)blockIdx.x << 12) | ((unsigned)t << 4);
  float2 v[16];
  if (first) {
    const float4* r4 = (const float4*)(srcRe + base);
    const float4* i4 = (const float4*)(srcIm + base);
#pragma unroll
    for (int k = 0; k < 4; ++k) {
      float4 r = r4[k], m = i4[k];
      v[4 * k + 0] = make_float2(r.x, m.x);
      v[4 * k + 1] = make_float2(r.y, m.y);
      v[4 * k + 2] = make_float2(r.z, m.z);
      v[4 * k + 3] = make_float2(r.w, m.w);
    }
  } else {
    const unsigned b = base >> 4;
    const unsigned W = (b ^ (b >> 1)) << 4;   // aligned 16-amp window
    const float4* s4 = (const float4*)(src2 + W);
    float2 w2[16];
#pragma unroll
    for (int k = 0; k < 8; ++k) {
      float4 x = s4[k];
      w2[2 * k] = make_float2(x.x, x.y);
      w2[2 * k + 1] = make_float2(x.z, x.w);
    }
    if (b & 1) {                               // flip bit 3 of window offset
#pragma unroll
      for (int k = 0; k < 8; ++k) { float2 tt = w2[k]; w2[k] = w2[k + 8]; w2[k + 8] = tt; }
    }
#pragma unroll
    for (int d = 0; d < 16; ++d) v[d] = w2[d ^ (d >> 1)];  // compile-time indices
  }
  apply4(v, U, layer, 21, 4);      // global bits 0..3  -> wires 21..18
  xchg2p<PA_PLANE>(lds, v,
       [&](int d) { unsigned j = ((unsigned)t << 4) | (unsigned)d; return (int)(j + (j >> 4)); },
       [&](int d) { unsigned j = (((unsigned)t >> 4) << 8) | ((unsigned)d << 4) | ((unsigned)t & 15); return (int)(j + (j >> 4)); });
  apply4(v, U, layer, 17, 4);      // bits 4..7 -> wires 17..14
  xchg2p<PA_PLANE>(lds, v,
       [&](int d) { unsigned j = (((unsigned)t >> 4) << 8) | ((unsigned)d << 4) | ((unsigned)t & 15); return (int)(j + (j >> 4)); },
       [&](int d) { unsigned j = ((unsigned)d << 8) | (unsigned)t; return (int)(j + (j >> 4)); });
  apply4(v, U, layer, 13, 4);      // bits 8..11 -> wires 13..10
  xchg2p<PA_PLANE>(lds, v,
       [&](int d) { unsigned j = ((unsigned)d << 8) | (unsigned)t; return (int)(j + (j >> 4)); },
       [&](int d) { unsigned j = ((unsigned)t << 4) | (unsigned)d; return (int)(j + (j >> 4)); });
  float4* o4 = (float4*)(dst + base);
#pragma unroll
  for (int k = 0; k < 8; ++k)
    o4[k] = make_float4(v[2 * k].x, v[2 * k].y, v[2 * k + 1].x, v[2 * k + 1].y);
}

// ---------------- pass B: gates on bits 12..21 (wires 9..0) ----------------
// block = 1024 h-rows (bits 12..21) x 8 columns (bits 0..2), bits 3..11 = blockIdx
// 512 threads x 16 amps; 72 KB LDS (two planes, e = h*9 + c) -> 2 blocks/CU overlap.
#define PB_PLANE 9216
__global__ __launch_bounds__(512, 4) void k_passB(const float2* __restrict__ src,
                                                  float2* __restrict__ dst,
                                                  const float* __restrict__ U,
                                                  int layer) {
  __shared__ float lds[2 * PB_PLANE];
  const int t = threadIdx.x;
  const int c = t & 7, u = t >> 3;   // u in 0..63
  const unsigned lowbase = ((unsigned)blockIdx.x << 3) | (unsigned)c;
  float2 v[16];
#pragma unroll
  for (int d = 0; d < 16; ++d) {
    unsigned h = (unsigned)u | ((unsigned)d << 6);   // d at h-bits 6..9 (wires 3..0)
    v[d] = src[(h << 12) | lowbase];
  }
  apply4(v, U, layer, 3, 4);
  xchg2p<PB_PLANE>(lds, v,
       [&](int d) { unsigned h = (unsigned)u | ((unsigned)d << 6); return (int)(h * 9u + (unsigned)c); },
       [&](int d) { unsigned h = ((unsigned)u & 3u) | ((unsigned)d << 2) | (((unsigned)u >> 2) << 6); return (int)(h * 9u + (unsigned)c); });
  apply4(v, U, layer, 7, 4);       // d = global 14..17 (wires 7..4)
  xchg2p<PB_PLANE>(lds, v,
       [&](int d) { unsigned h = ((unsigned)u & 3u) | ((unsigned)d << 2) | (((unsigned)u >> 2) << 6); return (int)(h * 9u + (unsigned)c); },
       [&](int d) { unsigned h = ((unsigned)d & 3u) | ((unsigned)u << 2) | (((unsigned)d >> 2) << 8); return (int)(h * 9u + (unsigned)c); });
  apply4(v, U, layer, 9, 2);       // d-bits 0,1 = global 12,13 (wires 9,8)
#pragma unroll
  for (int d = 0; d < 16; ++d) {
    unsigned h = ((unsigned)d & 3u) | ((unsigned)u << 2) | (((unsigned)d >> 2) << 8);
    dst[(h << 12) | lowbase] = v[d];
  }
}

// ---------------- pass B for the LAST layer, fused with expvals ----------------
// Same as k_passB but instead of storing, computes per-qubit Z-sums with the
// final-CNOT sign trick via a 4-bit Walsh fold over each thread's d-index.
// Thread amp j = (h<<12)|low, h = (d&3)|(u<<2)|((d>>2)<<8):
//   j12=d0, j13=d1, j14..19=u, j20=d2, j21=d3, j0..11=low.
// invGray x_k = XOR_{m>=k} j_m. Per-q sign = thread-fixed part ^ d-parity class:
//   q=0: D=(-1)^{d3}; q=1: C=(-1)^{d2^d3}; q=2..7: +/-C by parity(u>>(7-q));
//   q=8: +/-B=(-1)^{d1^d2^d3} by parity(u); q=9: +/-A=(-1)^{par(d)} by parity(u);
//   q=10..21: +/-A by invGray(low)_k ^ parity(u), k=21-q.
__global__ __launch_bounds__(512) void k_passB_ev(const float2* __restrict__ src,
                                                  const float* __restrict__ U,
                                                  float* __restrict__ partials,
                                                  int layer) {
  __shared__ float lds[2 * PB_PLANE];
  const int t = threadIdx.x;
  const int c = t & 7, u = t >> 3;
  const unsigned blk = blockIdx.x;
  const unsigned lowbase = (blk << 3) | (unsigned)c;
  float2 v[16];
#pragma unroll
  for (int d = 0; d < 16; ++d) {
    unsigned h = (unsigned)u | ((unsigned)d << 6);
    v[d] = src[(h << 12) | lowbase];
  }
  apply4(v, U, layer, 3, 4);
  xchg2p<PB_PLANE>(lds, v,
       [&](int d) { unsigned h = (unsigned)u | ((unsigned)d << 6); return (int)(h * 9u + (unsigned)c); },
       [&](int d) { unsigned h = ((unsigned)u & 3u) | ((unsigned)d << 2) | (((unsigned)u >> 2) << 6); return (int)(h * 9u + (unsigned)c); });
  apply4(v, U, layer, 7, 4);
  xchg2p<PB_PLANE>(lds, v,
       [&](int d) { unsigned h = ((unsigned)u & 3u) | ((unsigned)d << 2) | (((unsigned)u >> 2) << 6); return (int)(h * 9u + (unsigned)c); },
       [&](int d) { unsigned h = ((unsigned)d & 3u) | ((unsigned)u << 2) | (((unsigned)d >> 2) << 8); return (int)(h * 9u + (unsigned)c); });
  apply4(v, U, layer, 9, 2);

  // ---- fused expval epilogue ----
  float ps[16];
#pragma unroll
  for (int d = 0; d < 16; ++d) ps[d] = v[d].x * v[d].x + v[d].y * v[d].y;
  float s8[8], t8[8];
#pragma unroll
  for (int i = 0; i < 8; ++i) { s8[i] = ps[i] + ps[i + 8]; t8[i] = ps[i] - ps[i + 8]; }
  float Tot = ((s8[0] + s8[1]) + (s8[2] + s8[3])) + ((s8[4] + s8[5]) + (s8[6] + s8[7]));
  float D   = ((t8[0] + t8[1]) + (t8[2] + t8[3])) + ((t8[4] + t8[5]) + (t8[6] + t8[7]));
  float c2[4];
#pragma unroll
  for (int i = 0; i < 4; ++i) c2[i] = t8[i] - t8[i + 4];
  float C = (c2[0] + c2[1]) + (c2[2] + c2[3]);
  float b1_0 = c2[0] - c2[2], b1_1 = c2[1] - c2[3];
  float B = b1_0 + b1_1;
  float A = b1_0 - b1_1;

  unsigned low = lowbase;                    // j bits 0..11
  unsigned y = low; y ^= y >> 1; y ^= y >> 2; y ^= y >> 4; y ^= y >> 8;  // suffix-XOR
  unsigned pu = (unsigned)__popc((unsigned)u) & 1u;
  float acc[22];
  acc[0] = D;
  acc[1] = C;
#pragma unroll
  for (int q = 2; q <= 7; ++q)
    acc[q] = ((unsigned)__popc((unsigned)u >> (7 - q)) & 1u) ? -C : C;
  acc[8] = pu ? -B : B;
  acc[9] = pu ? -A : A;
#pragma unroll
  for (int q = 10; q <= 21; ++q)
    acc[q] = (((y >> (21 - q)) ^ pu) & 1u) ? -A : A;

  __syncthreads();                           // lds reuse for reduction
  float* red = lds;                          // 8 waves * 23
  const int lane = t & 63, wv = t >> 6;
#pragma unroll
  for (int q = 0; q < 22; ++q) {
    float s = acc[q];
    for (int off = 32; off > 0; off >>= 1) s += __shfl_down(s, off, 64);
    if (lane == 0) red[wv * 23 + q] = s;
  }
  {
    float s = Tot;
    for (int off = 32; off > 0; off >>= 1) s += __shfl_down(s, off, 64);
    if (lane == 0) red[wv * 23 + 22] = s;
  }
  __syncthreads();
  if (t < 23) {
    float s = 0.f;
#pragma unroll
    for (int w = 0; w < 8; ++w) s += red[w * 23 + t];
    partials[t * 512 + blk] = s;
  }
}

__global__ void k_final(const float* __restrict__ partials, float* __restrict__ out) {
  __shared__ double res[32];
  const int t = threadIdx.x;
  const int r = t >> 3, l8 = t & 7;
  if (r < 23) {
    double s = 0.0;
    const float* p = partials + r * 512 + l8 * 64;
    for (int k = 0; k < 64; ++k) s += (double)p[k];
    for (int off = 4; off > 0; off >>= 1) s += __shfl_down(s, off, 8);
    if (l8 == 0) res[r] = s;
  }
  __syncthreads();
  if (t < 22) out[t] = (float)(res[t] / res[22]);  // normalization folded in here
}

extern "C" void kernel_launch(void* const* d_in, const int* in_sizes, int n_in,
                              void* d_out, int out_size, void* d_ws, size_t ws_size,
                              hipStream_t stream) {
  const float* params = (const float*)d_in[0];   // [4][22][3]
  const float* sre = (const float*)d_in[1];      // [DIM]
  const float* sim = (const float*)d_in[2];      // [DIM]
  float* out = (float*)d_out;                    // [22]
  char* ws = (char*)d_ws;
  float* U = (float*)ws;                         // 88 * 8 floats
  float* partials = (float*)(ws + 4096);         // 23 * 512 floats
  float2* buf0 = (float2*)(ws + 131072);         // 32 MB
  float2* buf1 = buf0 + DIM;                     // 32 MB

  k_gates<<<1, 128, 0, stream>>>(params, U);
  // layer 0 (no permutation on input)
  k_passA<<<1024, 256, 0, stream>>>(sre, sim, nullptr, buf0, U, 0, 1);
  k_passB<<<512, 512, 0, stream>>>(buf0, buf1, U, 0);
  for (int l = 1; l < 3; ++l) {
    k_passA<<<1024, 256, 0, stream>>>(nullptr, nullptr, buf1, buf0, U, l, 0);
    k_passB<<<512, 512, 0, stream>>>(buf0, buf1, U, l);
  }
  k_passA<<<1024, 256, 0, stream>>>(nullptr, nullptr, buf1, buf0, U, 3, 0);
  k_passB_ev<<<512, 512, 0, stream>>>(buf0, U, partials, 3);
  k_final<<<1, 256, 0, stream>>>(partials, out);
}

// Round 5
// 237.129 us; speedup vs baseline: 1.2807x; 1.0348x over previous
//
#include <hip/hip_runtime.h>
#include <math.h>

#define NQ 22
#define DIM (1u << NQ)

typedef float v2f __attribute__((ext_vector_type(2)));

// ---------------- fused gate matrices: U = RZ * RY * RX, fp64 -> fp32 ----------------
__global__ void k_gates(const float* __restrict__ params, float* __restrict__ U) {
  int t = blockIdx.x * blockDim.x + threadIdx.x;
  if (t >= 88) return;               // t = l*22 + q
  const float* p = params + t * 3;
  double hx = 0.5 * (double)p[0], hy = 0.5 * (double)p[1], hz = 0.5 * (double)p[2];
  double cx = cos(hx), sx = sin(hx);
  double cy = cos(hy), sy = sin(hy);
  double cz = cos(hz), sz = sin(hz);
  double m00r = cy * cx, m00i = sy * sx;
  double m01r = -sy * cx, m01i = -cy * sx;
  double m10r = sy * cx, m10i = -cy * sx;
  double m11r = cy * cx, m11i = -sy * sx;
  float* o = U + t * 8;
  o[0] = (float)(cz * m00r + sz * m00i); o[1] = (float)(cz * m00i - sz * m00r);
  o[2] = (float)(cz * m01r + sz * m01i); o[3] = (float)(cz * m01i - sz * m01r);
  o[4] = (float)(cz * m10r - sz * m10i); o[5] = (float)(cz * m10i + sz * m10r);
  o[6] = (float)(cz * m11r - sz * m11i); o[7] = (float)(cz * m11i + sz * m11r);
}

// ---------------- packed gate application ----------------
// State: 16 amps/thread as RE[8], IM[8]; amp d lives in RE[d>>1] lane (d&1).
// Gate on amp-bit 0: partners share a pack -> scalar. Bits 1..3: element-wise v2f.

__device__ __forceinline__ void apply_bit0(v2f RE[8], v2f IM[8], const float* __restrict__ u) {
  float u0 = u[0], u1 = u[1], u2 = u[2], u3 = u[3], u4 = u[4], u5 = u[5], u6 = u[6], u7 = u[7];
#pragma unroll
  for (int k = 0; k < 8; ++k) {
    float a0r = RE[k].x, a0i = IM[k].x, a1r = RE[k].y, a1i = IM[k].y;
    float n0r = u0 * a0r - u1 * a0i + u2 * a1r - u3 * a1i;
    float n0i = u0 * a0i + u1 * a0r + u2 * a1i + u3 * a1r;
    float n1r = u4 * a0r - u5 * a0i + u6 * a1r - u7 * a1i;
    float n1i = u4 * a0i + u5 * a0r + u6 * a1i + u7 * a1r;
    RE[k].x = n0r; IM[k].x = n0i; RE[k].y = n1r; IM[k].y = n1i;
  }
}

template <int PB>   // pack-bit = amp-bit - 1
__device__ __forceinline__ void apply_bitP(v2f RE[8], v2f IM[8], const float* __restrict__ u) {
  float u0 = u[0], u1 = u[1], u2 = u[2], u3 = u[3], u4 = u[4], u5 = u[5], u6 = u[6], u7 = u[7];
#pragma unroll
  for (int m = 0; m < 4; ++m) {
    int k0 = ((m >> PB) << (PB + 1)) | (m & ((1 << PB) - 1));
    int k1 = k0 | (1 << PB);
    v2f a0r = RE[k0], a0i = IM[k0], a1r = RE[k1], a1i = IM[k1];
    v2f n0r = u0 * a0r - u1 * a0i + u2 * a1r - u3 * a1i;
    v2f n0i = u0 * a0i + u1 * a0r + u2 * a1i + u3 * a1r;
    v2f n1r = u4 * a0r - u5 * a0i + u6 * a1r - u7 * a1i;
    v2f n1i = u4 * a0i + u5 * a0r + u6 * a1i + u7 * a1r;
    RE[k0] = n0r; IM[k0] = n0i; RE[k1] = n1r; IM[k1] = n1i;
  }
}

// amp-bit b uses wire (wtop - b); U entry stride 8 floats
__device__ __forceinline__ void apply4p(v2f RE[8], v2f IM[8], const float* __restrict__ U,
                                        int l, int wtop, int nb) {
  const float* base = U + ((l * 22 + wtop) << 3);
  apply_bit0(RE, IM, base);
  if (nb > 1) apply_bitP<0>(RE, IM, base - 8);
  if (nb > 2) apply_bitP<1>(RE, IM, base - 16);
  if (nb > 3) apply_bitP<2>(RE, IM, base - 24);
}

// float2 (b64) LDS exchange; wi/ri return PHYSICAL (pre-swizzled) indices. 2 barriers.
template <typename WI, typename RI>
__device__ __forceinline__ void xchgP(float2* lds2, v2f RE[8], v2f IM[8], WI wi, RI ri) {
  __syncthreads();
#pragma unroll
  for (int d = 0; d < 16; ++d) {
    float2 a;
    if (d & 1) a = make_float2(RE[d >> 1].y, IM[d >> 1].y);
    else       a = make_float2(RE[d >> 1].x, IM[d >> 1].x);
    lds2[wi(d)] = a;
  }
  __syncthreads();
#pragma unroll
  for (int d = 0; d < 16; ++d) {
    float2 a = lds2[ri(d)];
    if (d & 1) { RE[d >> 1].y = a.x; IM[d >> 1].y = a.y; }
    else       { RE[d >> 1].x = a.x; IM[d >> 1].x = a.y; }
  }
}

// ---------------- pass A: gates on bits 0..11 (wires 21..10) ----------------
// block = 4096 contiguous amps, 256 threads x 16 amps.
// Gray-gather (layers>=1): coalesced window load + compile-time register permute:
//   G(b*16+d) = ((b^(b>>1))<<4) | ((d^(d>>1)) ^ ((b&1)<<3))
__global__ __launch_bounds__(256, 4) void k_passA(const float* __restrict__ srcRe,
                                                  const float* __restrict__ srcIm,
                                                  const float2* __restrict__ src2,
                                                  float2* __restrict__ dst,
                                                  const float* __restrict__ U,
                                                  int layer, int first) {
  __shared__ float2 lds2[4096];   // 32 KB; physical idx = j ^ (j>>4)
  const int t = threadIdx.x;
  const unsigned base = ((unsigned)blockIdx.x << 12) | ((unsigned)t << 4);
  v2f RE[8], IM[8];
  if (first) {
    const float4* r4 = (const float4*)(srcRe + base);
    const float4* i4 = (const float4*)(srcIm + base);
#pragma unroll
    for (int k = 0; k < 4; ++k) {
      float4 r = r4[k], m = i4[k];
      RE[2 * k].x     = r.x; RE[2 * k].y     = r.y;
      IM[2 * k].x     = m.x; IM[2 * k].y     = m.y;
      RE[2 * k + 1].x = r.z; RE[2 * k + 1].y = r.w;
      IM[2 * k + 1].x = m.z; IM[2 * k + 1].y = m.w;
    }
  } else {
    const unsigned b = base >> 4;
    const unsigned W = (b ^ (b >> 1)) << 4;   // aligned 16-amp window
    const float4* s4 = (const float4*)(src2 + W);
    v2f WR[8], WI[8];
#pragma unroll
    for (int k = 0; k < 8; ++k) {
      float4 x = s4[k];
      WR[k].x = x.x; WR[k].y = x.z;
      WI[k].x = x.y; WI[k].y = x.w;
    }
    if (b & 1) {                               // flip bit 3 of window offset
#pragma unroll
      for (int k = 0; k < 4; ++k) {
        v2f tr = WR[k]; WR[k] = WR[k + 4]; WR[k + 4] = tr;
        v2f ti = WI[k]; WI[k] = WI[k + 4]; WI[k + 4] = ti;
      }
    }
    // v[d] = w[d ^ (d>>1)]; packed: src pack j = ((2k)^k)>>1, swap lanes if k odd
#pragma unroll
    for (int k = 0; k < 8; ++k) {
      const int s = (2 * k) ^ k;
      const int j = s >> 1;
      if (s & 1) {
        RE[k].x = WR[j].y; RE[k].y = WR[j].x;
        IM[k].x = WI[j].y; IM[k].y = WI[j].x;
      } else {
        RE[k] = WR[j]; IM[k] = WI[j];
      }
    }
  }
  auto wA = [&](int d) { unsigned j = ((unsigned)t << 4) | (unsigned)d; return (int)(j ^ (j >> 4)); };
  auto rB = [&](int d) { unsigned j = (((unsigned)t >> 4) << 8) | ((unsigned)d << 4) | ((unsigned)t & 15); return (int)(j ^ (j >> 4)); };
  auto rC = [&](int d) { unsigned j = ((unsigned)d << 8) | (unsigned)t; return (int)(j ^ (j >> 4)); };

  apply4p(RE, IM, U, layer, 21, 4);      // amp bits 0..3  -> wires 21..18
  xchgP(lds2, RE, IM, wA, rB);
  apply4p(RE, IM, U, layer, 17, 4);      // bits 4..7 -> wires 17..14
  xchgP(lds2, RE, IM, rB, rC);
  apply4p(RE, IM, U, layer, 13, 4);      // bits 8..11 -> wires 13..10
  xchgP(lds2, RE, IM, rC, wA);
  float4* o4 = (float4*)(dst + base);
#pragma unroll
  for (int k = 0; k < 8; ++k)
    o4[k] = make_float4(RE[k].x, IM[k].x, RE[k].y, IM[k].y);
}

// ---------------- pass B: gates on bits 12..21 (wires 9..0) ----------------
// block = 1024 h-rows (bits 12..21) x 8 cols (bits 0..2), bits 3..11 = blockIdx
// 512 threads x 16 amps; 72 KB float2 LDS (idx = h*9 + c) -> 2 blocks/CU.
__global__ __launch_bounds__(512, 4) void k_passB(const float2* __restrict__ src,
                                                  float2* __restrict__ dst,
                                                  const float* __restrict__ U,
                                                  int layer) {
  __shared__ float2 lds2[9216];
  const int t = threadIdx.x;
  const int c = t & 7, u = t >> 3;   // u in 0..63
  const unsigned lowbase = ((unsigned)blockIdx.x << 3) | (unsigned)c;
  v2f RE[8], IM[8];
#pragma unroll
  for (int d = 0; d < 16; ++d) {
    unsigned h = (unsigned)u | ((unsigned)d << 6);   // d at h-bits 6..9 (wires 3..0)
    float2 a = src[(h << 12) | lowbase];
    if (d & 1) { RE[d >> 1].y = a.x; IM[d >> 1].y = a.y; }
    else       { RE[d >> 1].x = a.x; IM[d >> 1].x = a.y; }
  }
  apply4p(RE, IM, U, layer, 3, 4);
  xchgP(lds2, RE, IM,
       [&](int d) { unsigned h = (unsigned)u | ((unsigned)d << 6); return (int)(h * 9u + (unsigned)c); },
       [&](int d) { unsigned h = ((unsigned)u & 3u) | ((unsigned)d << 2) | (((unsigned)u >> 2) << 6); return (int)(h * 9u + (unsigned)c); });
  apply4p(RE, IM, U, layer, 7, 4);     // d = global 14..17 (wires 7..4)
  xchgP(lds2, RE, IM,
       [&](int d) { unsigned h = ((unsigned)u & 3u) | ((unsigned)d << 2) | (((unsigned)u >> 2) << 6); return (int)(h * 9u + (unsigned)c); },
       [&](int d) { unsigned h = ((unsigned)d & 3u) | ((unsigned)u << 2) | (((unsigned)d >> 2) << 8); return (int)(h * 9u + (unsigned)c); });
  apply4p(RE, IM, U, layer, 9, 2);     // d-bits 0,1 = global 12,13 (wires 9,8)
#pragma unroll
  for (int d = 0; d < 16; ++d) {
    unsigned h = ((unsigned)d & 3u) | ((unsigned)u << 2) | (((unsigned)d >> 2) << 8);
    float2 a;
    if (d & 1) a = make_float2(RE[d >> 1].y, IM[d >> 1].y);
    else       a = make_float2(RE[d >> 1].x, IM[d >> 1].x);
    dst[(h << 12) | lowbase] = a;
  }
}

// ---------------- last-layer pass B fused with expvals (final-CNOT sign trick) ----------------
__global__ __launch_bounds__(512) void k_passB_ev(const float2* __restrict__ src,
                                                  const float* __restrict__ U,
                                                  float* __restrict__ partials,
                                                  int layer) {
  __shared__ float2 lds2[9216];
  const int t = threadIdx.x;
  const int c = t & 7, u = t >> 3;
  const unsigned blk = blockIdx.x;
  const unsigned lowbase = (blk << 3) | (unsigned)c;
  v2f RE[8], IM[8];
#pragma unroll
  for (int d = 0; d < 16; ++d) {
    unsigned h = (unsigned)u | ((unsigned)d << 6);
    float2 a = src[(h << 12) | lowbase];
    if (d & 1) { RE[d >> 1].y = a.x; IM[d >> 1].y = a.y; }
    else       { RE[d >> 1].x = a.x; IM[d >> 1].x = a.y; }
  }
  apply4p(RE, IM, U, layer, 3, 4);
  xchgP(lds2, RE, IM,
       [&](int d) { unsigned h = (unsigned)u | ((unsigned)d << 6); return (int)(h * 9u + (unsigned)c); },
       [&](int d) { unsigned h = ((unsigned)u & 3u) | ((unsigned)d << 2) | (((unsigned)u >> 2) << 6); return (int)(h * 9u + (unsigned)c); });
  apply4p(RE, IM, U, layer, 7, 4);
  xchgP(lds2, RE, IM,
       [&](int d) { unsigned h = ((unsigned)u & 3u) | ((unsigned)d << 2) | (((unsigned)u >> 2) << 6); return (int)(h * 9u + (unsigned)c); },
       [&](int d) { unsigned h = ((unsigned)d & 3u) | ((unsigned)u << 2) | (((unsigned)d >> 2) << 8); return (int)(h * 9u + (unsigned)c); });
  apply4p(RE, IM, U, layer, 9, 2);

  // ---- fused expval epilogue: Walsh fold over d (packed) ----
  v2f PS[8];
#pragma unroll
  for (int k = 0; k < 8; ++k) PS[k] = RE[k] * RE[k] + IM[k] * IM[k];
  v2f S[4], T[4];
#pragma unroll
  for (int k = 0; k < 4; ++k) { S[k] = PS[k] + PS[k + 4]; T[k] = PS[k] - PS[k + 4]; }
  float Tot = (S[0].x + S[0].y) + (S[1].x + S[1].y) + (S[2].x + S[2].y) + (S[3].x + S[3].y);
  float D   = (T[0].x + T[0].y) + (T[1].x + T[1].y) + (T[2].x + T[2].y) + (T[3].x + T[3].y);
  v2f C2[2];
  C2[0] = T[0] - T[2]; C2[1] = T[1] - T[3];
  float C = (C2[0].x + C2[0].y) + (C2[1].x + C2[1].y);
  float b1_0 = C2[0].x - C2[1].x, b1_1 = C2[0].y - C2[1].y;
  float B = b1_0 + b1_1;
  float A = b1_0 - b1_1;

  unsigned low = lowbase;
  unsigned y = low; y ^= y >> 1; y ^= y >> 2; y ^= y >> 4; y ^= y >> 8;  // suffix-XOR
  unsigned pu = (unsigned)__popc((unsigned)u) & 1u;
  float acc[22];
  acc[0] = D;
  acc[1] = C;
#pragma unroll
  for (int q = 2; q <= 7; ++q)
    acc[q] = ((unsigned)__popc((unsigned)u >> (7 - q)) & 1u) ? -C : C;
  acc[8] = pu ? -B : B;
  acc[9] = pu ? -A : A;
#pragma unroll
  for (int q = 10; q <= 21; ++q)
    acc[q] = (((y >> (21 - q)) ^ pu) & 1u) ? -A : A;

  __syncthreads();
  float* red = (float*)lds2;                 // 8 waves * 23
  const int lane = t & 63, wv = t >> 6;
#pragma unroll
  for (int q = 0; q < 22; ++q) {
    float s = acc[q];
    for (int off = 32; off > 0; off >>= 1) s += __shfl_down(s, off, 64);
    if (lane == 0) red[wv * 23 + q] = s;
  }
  {
    float s = Tot;
    for (int off = 32; off > 0; off >>= 1) s += __shfl_down(s, off, 64);
    if (lane == 0) red[wv * 23 + 22] = s;
  }
  __syncthreads();
  if (t < 23) {
    float s = 0.f;
#pragma unroll
    for (int w = 0; w < 8; ++w) s += red[w * 23 + t];
    partials[t * 512 + blk] = s;
  }
}

__global__ void k_final(const float* __restrict__ partials, float* __restrict__ out) {
  __shared__ double res[32];
  const int t = threadIdx.x;
  const int r = t >> 3, l8 = t & 7;
  if (r < 23) {
    double s = 0.0;
    const float* p = partials + r * 512 + l8 * 64;
    for (int k = 0; k < 64; ++k) s += (double)p[k];
    for (int off = 4; off > 0; off >>= 1) s += __shfl_down(s, off, 8);
    if (l8 == 0) res[r] = s;
  }
  __syncthreads();
  if (t < 22) out[t] = (float)(res[t] / res[22]);  // normalization folded in
}

extern "C" void kernel_launch(void* const* d_in, const int* in_sizes, int n_in,
                              void* d_out, int out_size, void* d_ws, size_t ws_size,
                              hipStream_t stream) {
  const float* params = (const float*)d_in[0];   // [4][22][3]
  const float* sre = (const float*)d_in[1];      // [DIM]
  const float* sim = (const float*)d_in[2];      // [DIM]
  float* out = (float*)d_out;                    // [22]
  char* ws = (char*)d_ws;
  float* U = (float*)ws;                         // 88 * 8 floats
  float* partials = (float*)(ws + 4096);         // 23 * 512 floats
  float2* buf0 = (float2*)(ws + 131072);         // 32 MB
  float2* buf1 = buf0 + DIM;                     // 32 MB

  k_gates<<<1, 128, 0, stream>>>(params, U);
  // layer 0 (no permutation on input)
  k_passA<<<1024, 256, 0, stream>>>(sre, sim, nullptr, buf0, U, 0, 1);
  k_passB<<<512, 512, 0, stream>>>(buf0, buf1, U, 0);
  for (int l = 1; l < 3; ++l) {
    k_passA<<<1024, 256, 0, stream>>>(nullptr, nullptr, buf1, buf0, U, l, 0);
    k_passB<<<512, 512, 0, stream>>>(buf0, buf1, U, l);
  }
  k_passA<<<1024, 256, 0, stream>>>(nullptr, nullptr, buf1, buf0, U, 3, 0);
  k_passB_ev<<<512, 512, 0, stream>>>(buf0, U, partials, 3);
  k_final<<<1, 256, 0, stream>>>(partials, out);
}

// Round 6
// 235.107 us; speedup vs baseline: 1.2918x; 1.0086x over previous
//
#include <hip/hip_runtime.h>
#include <math.h>

#define NQ 22
#define DIM (1u << NQ)

typedef float v2f __attribute__((ext_vector_type(2)));

// ---------------- fused gate matrices: U = RZ * RY * RX, fp64 -> fp32 ----------------
__global__ void k_gates(const float* __restrict__ params, float* __restrict__ U) {
  int t = blockIdx.x * blockDim.x + threadIdx.x;
  if (t >= 88) return;               // t = l*22 + q
  const float* p = params + t * 3;
  double hx = 0.5 * (double)p[0], hy = 0.5 * (double)p[1], hz = 0.5 * (double)p[2];
  double cx = cos(hx), sx = sin(hx);
  double cy = cos(hy), sy = sin(hy);
  double cz = cos(hz), sz = sin(hz);
  double m00r = cy * cx, m00i = sy * sx;
  double m01r = -sy * cx, m01i = -cy * sx;
  double m10r = sy * cx, m10i = -cy * sx;
  double m11r = cy * cx, m11i = -sy * sx;
  float* o = U + t * 8;
  o[0] = (float)(cz * m00r + sz * m00i); o[1] = (float)(cz * m00i - sz * m00r);
  o[2] = (float)(cz * m01r + sz * m01i); o[3] = (float)(cz * m01i - sz * m01r);
  o[4] = (float)(cz * m10r - sz * m10i); o[5] = (float)(cz * m10i + sz * m10r);
  o[6] = (float)(cz * m11r - sz * m11i); o[7] = (float)(cz * m11i + sz * m11r);
}

// ---------------- packed gate application (N packs of 2 amps) ----------------
template <int NP>
__device__ __forceinline__ void apply_bit0(v2f RE[NP], v2f IM[NP], const float* __restrict__ u) {
  float u0 = u[0], u1 = u[1], u2 = u[2], u3 = u[3], u4 = u[4], u5 = u[5], u6 = u[6], u7 = u[7];
#pragma unroll
  for (int k = 0; k < NP; ++k) {
    float a0r = RE[k].x, a0i = IM[k].x, a1r = RE[k].y, a1i = IM[k].y;
    float n0r = u0 * a0r - u1 * a0i + u2 * a1r - u3 * a1i;
    float n0i = u0 * a0i + u1 * a0r + u2 * a1i + u3 * a1r;
    float n1r = u4 * a0r - u5 * a0i + u6 * a1r - u7 * a1i;
    float n1i = u4 * a0i + u5 * a0r + u6 * a1i + u7 * a1r;
    RE[k].x = n0r; IM[k].x = n0i; RE[k].y = n1r; IM[k].y = n1i;
  }
}

template <int NP, int PB>   // pack-bit = amp-bit - 1
__device__ __forceinline__ void apply_bitP(v2f RE[NP], v2f IM[NP], const float* __restrict__ u) {
  float u0 = u[0], u1 = u[1], u2 = u[2], u3 = u[3], u4 = u[4], u5 = u[5], u6 = u[6], u7 = u[7];
#pragma unroll
  for (int m = 0; m < NP / 2; ++m) {
    int k0 = ((m >> PB) << (PB + 1)) | (m & ((1 << PB) - 1));
    int k1 = k0 | (1 << PB);
    v2f a0r = RE[k0], a0i = IM[k0], a1r = RE[k1], a1i = IM[k1];
    v2f n0r = u0 * a0r - u1 * a0i + u2 * a1r - u3 * a1i;
    v2f n0i = u0 * a0i + u1 * a0r + u2 * a1i + u3 * a1r;
    v2f n1r = u4 * a0r - u5 * a0i + u6 * a1r - u7 * a1i;
    v2f n1i = u4 * a0i + u5 * a0r + u6 * a1i + u7 * a1r;
    RE[k0] = n0r; IM[k0] = n0i; RE[k1] = n1r; IM[k1] = n1i;
  }
}

// 4 amp-bits over 8 packs; amp-bit b uses wire (wtop - b)
__device__ __forceinline__ void apply4p(v2f RE[8], v2f IM[8], const float* __restrict__ U,
                                        int l, int wtop) {
  const float* base = U + ((l * 22 + wtop) << 3);
  apply_bit0<8>(RE, IM, base);
  apply_bitP<8, 0>(RE, IM, base - 8);
  apply_bitP<8, 1>(RE, IM, base - 16);
  apply_bitP<8, 2>(RE, IM, base - 24);
}

// 5 amp-bits over 16 packs
__device__ __forceinline__ void apply5p(v2f RE[16], v2f IM[16], const float* __restrict__ U,
                                        int l, int wtop) {
  const float* base = U + ((l * 22 + wtop) << 3);
  apply_bit0<16>(RE, IM, base);
  apply_bitP<16, 0>(RE, IM, base - 8);
  apply_bitP<16, 1>(RE, IM, base - 16);
  apply_bitP<16, 2>(RE, IM, base - 24);
  apply_bitP<16, 3>(RE, IM, base - 32);
}

// float2 (b64) LDS exchange for 16-amp state; 2 barriers.
template <typename WI, typename RI>
__device__ __forceinline__ void xchgP(float2* lds2, v2f RE[8], v2f IM[8], WI wi, RI ri) {
  __syncthreads();
#pragma unroll
  for (int d = 0; d < 16; ++d) {
    float2 a;
    if (d & 1) a = make_float2(RE[d >> 1].y, IM[d >> 1].y);
    else       a = make_float2(RE[d >> 1].x, IM[d >> 1].x);
    lds2[wi(d)] = a;
  }
  __syncthreads();
#pragma unroll
  for (int d = 0; d < 16; ++d) {
    float2 a = lds2[ri(d)];
    if (d & 1) { RE[d >> 1].y = a.x; IM[d >> 1].y = a.y; }
    else       { RE[d >> 1].x = a.x; IM[d >> 1].x = a.y; }
  }
}

// ---------------- pass A: gates on bits 0..11 (wires 21..10) ----------------
// block = 4096 contiguous amps, 256 threads x 16 amps.
// Gray-gather (layers>=1): coalesced window load + compile-time register permute:
//   G(b*16+d) = ((b^(b>>1))<<4) | ((d^(d>>1)) ^ ((b&1)<<3))
__global__ __launch_bounds__(256, 4) void k_passA(const float* __restrict__ srcRe,
                                                  const float* __restrict__ srcIm,
                                                  const float2* __restrict__ src2,
                                                  float2* __restrict__ dst,
                                                  const float* __restrict__ U,
                                                  int layer, int first) {
  __shared__ float2 lds2[4096];   // 32 KB; physical idx = j ^ (j>>4)
  const int t = threadIdx.x;
  const unsigned base = ((unsigned)blockIdx.x << 12) | ((unsigned)t << 4);
  v2f RE[8], IM[8];
  if (first) {
    const float4* r4 = (const float4*)(srcRe + base);
    const float4* i4 = (const float4*)(srcIm + base);
#pragma unroll
    for (int k = 0; k < 4; ++k) {
      float4 r = r4[k], m = i4[k];
      RE[2 * k].x     = r.x; RE[2 * k].y     = r.y;
      IM[2 * k].x     = m.x; IM[2 * k].y     = m.y;
      RE[2 * k + 1].x = r.z; RE[2 * k + 1].y = r.w;
      IM[2 * k + 1].x = m.z; IM[2 * k + 1].y = m.w;
    }
  } else {
    const unsigned b = base >> 4;
    const unsigned W = (b ^ (b >> 1)) << 4;   // aligned 16-amp window
    const float4* s4 = (const float4*)(src2 + W);
    v2f WR[8], WI[8];
#pragma unroll
    for (int k = 0; k < 8; ++k) {
      float4 x = s4[k];
      WR[k].x = x.x; WR[k].y = x.z;
      WI[k].x = x.y; WI[k].y = x.w;
    }
    if (b & 1) {                               // flip bit 3 of window offset
#pragma unroll
      for (int k = 0; k < 4; ++k) {
        v2f tr = WR[k]; WR[k] = WR[k + 4]; WR[k + 4] = tr;
        v2f ti = WI[k]; WI[k] = WI[k + 4]; WI[k + 4] = ti;
      }
    }
    // v[d] = w[d ^ (d>>1)]; packed: src pack j = ((2k)^k)>>1, swap lanes if odd
#pragma unroll
    for (int k = 0; k < 8; ++k) {
      const int s = (2 * k) ^ k;
      const int j = s >> 1;
      if (s & 1) {
        RE[k].x = WR[j].y; RE[k].y = WR[j].x;
        IM[k].x = WI[j].y; IM[k].y = WI[j].x;
      } else {
        RE[k] = WR[j]; IM[k] = WI[j];
      }
    }
  }
  auto wA = [&](int d) { unsigned j = ((unsigned)t << 4) | (unsigned)d; return (int)(j ^ (j >> 4)); };
  auto rB = [&](int d) { unsigned j = (((unsigned)t >> 4) << 8) | ((unsigned)d << 4) | ((unsigned)t & 15); return (int)(j ^ (j >> 4)); };
  auto rC = [&](int d) { unsigned j = ((unsigned)d << 8) | (unsigned)t; return (int)(j ^ (j >> 4)); };

  apply4p(RE, IM, U, layer, 21);      // amp bits 0..3  -> wires 21..18
  xchgP(lds2, RE, IM, wA, rB);
  apply4p(RE, IM, U, layer, 17);      // bits 4..7 -> wires 17..14
  xchgP(lds2, RE, IM, rB, rC);
  apply4p(RE, IM, U, layer, 13);      // bits 8..11 -> wires 13..10
  xchgP(lds2, RE, IM, rC, wA);
  float4* o4 = (float4*)(dst + base);
#pragma unroll
  for (int k = 0; k < 8; ++k)
    o4[k] = make_float4(RE[k].x, IM[k].x, RE[k].y, IM[k].y);
}

// ---------------- pass B: gates on bits 12..21 (wires 9..0) ----------------
// block = 1024 h-rows x 16 cols (bits 0..3), bits 4..11 = blockIdx; grid 256.
// 512 threads x 32 amps; wires split 5+5 with ONE LDS exchange (4 barriers).
// All global segments = 16 cols x 8 B = 128 B full lines.
// LDS swizzle: e = (h<<4 | (c ^ ((h^(h>>5))&15))) ^ (((h>>5)&1)<<4)
//   -> 2-way max bank aliasing for both h=u|(d<<5) writes and h=d|(u<<5) reads.
__device__ __forceinline__ int pb_lds_idx(unsigned h, unsigned c) {
  unsigned e = (h << 4) | (c ^ ((h ^ (h >> 5)) & 15u));
  return (int)(e ^ (((h >> 5) & 1u) << 4));
}

__global__ __launch_bounds__(512, 2) void k_passB(const float2* __restrict__ src,
                                                  float2* __restrict__ dst,
                                                  const float* __restrict__ U,
                                                  int layer) {
  __shared__ float lds[16384];   // 64 KB single plane
  const int t = threadIdx.x;
  const unsigned c = (unsigned)(t & 15), u = (unsigned)(t >> 4);   // u in 0..31
  const unsigned lowbase = ((unsigned)blockIdx.x << 4) | c;
  v2f RE[16], IM[16];
#pragma unroll
  for (int d = 0; d < 32; ++d) {
    unsigned h = u | ((unsigned)d << 5);     // d at h-bits 5..9 (wires 4..0)
    float2 a = src[(h << 12) | lowbase];
    if (d & 1) { RE[d >> 1].y = a.x; IM[d >> 1].y = a.y; }
    else       { RE[d >> 1].x = a.x; IM[d >> 1].x = a.y; }
  }
  apply5p(RE, IM, U, layer, 4);              // wires 4..0
  // exchange: d moves to h-bits 0..4 (re plane, then im plane; read back in-place)
  __syncthreads();
#pragma unroll
  for (int d = 0; d < 32; ++d) {
    unsigned h = u | ((unsigned)d << 5);
    lds[pb_lds_idx(h, c)] = (d & 1) ? RE[d >> 1].y : RE[d >> 1].x;
  }
  __syncthreads();
#pragma unroll
  for (int d = 0; d < 32; ++d) {
    unsigned h = (unsigned)d | (u << 5);
    float a = lds[pb_lds_idx(h, c)];
    if (d & 1) RE[d >> 1].y = a; else RE[d >> 1].x = a;
  }
  __syncthreads();
#pragma unroll
  for (int d = 0; d < 32; ++d) {
    unsigned h = u | ((unsigned)d << 5);
    lds[pb_lds_idx(h, c)] = (d & 1) ? IM[d >> 1].y : IM[d >> 1].x;
  }
  __syncthreads();
#pragma unroll
  for (int d = 0; d < 32; ++d) {
    unsigned h = (unsigned)d | (u << 5);
    float a = lds[pb_lds_idx(h, c)];
    if (d & 1) IM[d >> 1].y = a; else IM[d >> 1].x = a;
  }
  apply5p(RE, IM, U, layer, 9);              // d-bit b = global 12+b -> wires 9..5
#pragma unroll
  for (int d = 0; d < 32; ++d) {
    unsigned h = (unsigned)d | (u << 5);
    float2 a;
    if (d & 1) a = make_float2(RE[d >> 1].y, IM[d >> 1].y);
    else       a = make_float2(RE[d >> 1].x, IM[d >> 1].x);
    dst[(h << 12) | lowbase] = a;
  }
}

// ---------------- last-layer pass B fused with expvals (final-CNOT sign trick) ----------------
// Thread amp j: bits 0..11 = lowbase, 12..16 = d, 17..21 = u. invGray x_k = XOR_{m>=k} j_m:
//  q=0..4:  sign = parity(u >> (4-q))            -> +/-Tot
//  q=5..9:  sign = parity(d >> (9-q)) ^ pu       -> +/-W_{9-q} (suffix-parity Walsh)
//  q=10..21: sign = y_{21-q} ^ pd ^ pu           -> +/-W0, y = suffix-XOR of low
__global__ __launch_bounds__(512, 2) void k_passB_ev(const float2* __restrict__ src,
                                                     const float* __restrict__ U,
                                                     float* __restrict__ partials,
                                                     int layer) {
  __shared__ float lds[16384];
  const int t = threadIdx.x;
  const unsigned c = (unsigned)(t & 15), u = (unsigned)(t >> 4);
  const unsigned blk = blockIdx.x;
  const unsigned lowbase = (blk << 4) | c;
  v2f RE[16], IM[16];
#pragma unroll
  for (int d = 0; d < 32; ++d) {
    unsigned h = u | ((unsigned)d << 5);
    float2 a = src[(h << 12) | lowbase];
    if (d & 1) { RE[d >> 1].y = a.x; IM[d >> 1].y = a.y; }
    else       { RE[d >> 1].x = a.x; IM[d >> 1].x = a.y; }
  }
  apply5p(RE, IM, U, layer, 4);
  __syncthreads();
#pragma unroll
  for (int d = 0; d < 32; ++d) {
    unsigned h = u | ((unsigned)d << 5);
    lds[pb_lds_idx(h, c)] = (d & 1) ? RE[d >> 1].y : RE[d >> 1].x;
  }
  __syncthreads();
#pragma unroll
  for (int d = 0; d < 32; ++d) {
    unsigned h = (unsigned)d | (u << 5);
    float a = lds[pb_lds_idx(h, c)];
    if (d & 1) RE[d >> 1].y = a; else RE[d >> 1].x = a;
  }
  __syncthreads();
#pragma unroll
  for (int d = 0; d < 32; ++d) {
    unsigned h = u | ((unsigned)d << 5);
    lds[pb_lds_idx(h, c)] = (d & 1) ? IM[d >> 1].y : IM[d >> 1].x;
  }
  __syncthreads();
#pragma unroll
  for (int d = 0; d < 32; ++d) {
    unsigned h = (unsigned)d | (u << 5);
    float a = lds[pb_lds_idx(h, c)];
    if (d & 1) IM[d >> 1].y = a; else IM[d >> 1].x = a;
  }
  apply5p(RE, IM, U, layer, 9);

  // ---- fused expval epilogue: suffix-parity Walsh fold over 5 d-bits ----
  v2f PS[16];
#pragma unroll
  for (int k = 0; k < 16; ++k) PS[k] = RE[k] * RE[k] + IM[k] * IM[k];
  v2f S4[8], B4[8];
#pragma unroll
  for (int k = 0; k < 8; ++k) { S4[k] = PS[k] + PS[k + 8]; B4[k] = PS[k] - PS[k + 8]; }
  float Tot = 0.f, W4 = 0.f;
#pragma unroll
  for (int k = 0; k < 8; ++k) { Tot += S4[k].x + S4[k].y; W4 += B4[k].x + B4[k].y; }
  v2f B3[4];
#pragma unroll
  for (int k = 0; k < 4; ++k) B3[k] = B4[k] - B4[k + 4];
  float W3 = (B3[0].x + B3[0].y) + (B3[1].x + B3[1].y) + (B3[2].x + B3[2].y) + (B3[3].x + B3[3].y);
  v2f B2[2];
  B2[0] = B3[0] - B3[2]; B2[1] = B3[1] - B3[3];
  float W2 = (B2[0].x + B2[0].y) + (B2[1].x + B2[1].y);
  v2f B1 = B2[0] - B2[1];
  float W1 = B1.x + B1.y;
  float W0 = B1.x - B1.y;

  unsigned y = lowbase; y ^= y >> 1; y ^= y >> 2; y ^= y >> 4; y ^= y >> 8;  // suffix-XOR
  unsigned pu = (unsigned)__popc(u) & 1u;
  float acc[22];
#pragma unroll
  for (int q = 0; q <= 4; ++q)
    acc[q] = ((unsigned)__popc(u >> (4 - q)) & 1u) ? -Tot : Tot;
  {
    float W[5] = {W0, W1, W2, W3, W4};
#pragma unroll
    for (int q = 5; q <= 9; ++q)
      acc[q] = pu ? -W[9 - q] : W[9 - q];
  }
#pragma unroll
  for (int q = 10; q <= 21; ++q)
    acc[q] = (((y >> (21 - q)) ^ pu) & 1u) ? -W0 : W0;

  __syncthreads();
  float* red = lds;                          // 8 waves * 23
  const int lane = t & 63, wv = t >> 6;
#pragma unroll
  for (int q = 0; q < 22; ++q) {
    float s = acc[q];
    for (int off = 32; off > 0; off >>= 1) s += __shfl_down(s, off, 64);
    if (lane == 0) red[wv * 23 + q] = s;
  }
  {
    float s = Tot;
    for (int off = 32; off > 0; off >>= 1) s += __shfl_down(s, off, 64);
    if (lane == 0) red[wv * 23 + 22] = s;
  }
  __syncthreads();
  if (t < 23) {
    float s = 0.f;
#pragma unroll
    for (int w = 0; w < 8; ++w) s += red[w * 23 + t];
    partials[t * 256 + blk] = s;
  }
}

__global__ void k_final(const float* __restrict__ partials, float* __restrict__ out) {
  __shared__ double res[32];
  const int t = threadIdx.x;
  const int r = t >> 3, l8 = t & 7;
  if (r < 23) {
    double s = 0.0;
    const float* p = partials + r * 256 + l8 * 32;
    for (int k = 0; k < 32; ++k) s += (double)p[k];
    for (int off = 4; off > 0; off >>= 1) s += __shfl_down(s, off, 8);
    if (l8 == 0) res[r] = s;
  }
  __syncthreads();
  if (t < 22) out[t] = (float)(res[t] / res[22]);  // normalization folded in
}

extern "C" void kernel_launch(void* const* d_in, const int* in_sizes, int n_in,
                              void* d_out, int out_size, void* d_ws, size_t ws_size,
                              hipStream_t stream) {
  const float* params = (const float*)d_in[0];   // [4][22][3]
  const float* sre = (const float*)d_in[1];      // [DIM]
  const float* sim = (const float*)d_in[2];      // [DIM]
  float* out = (float*)d_out;                    // [22]
  char* ws = (char*)d_ws;
  float* U = (float*)ws;                         // 88 * 8 floats
  float* partials = (float*)(ws + 4096);         // 23 * 256 floats
  float2* buf0 = (float2*)(ws + 131072);         // 32 MB
  float2* buf1 = buf0 + DIM;                     // 32 MB

  k_gates<<<1, 128, 0, stream>>>(params, U);
  // layer 0 (no permutation on input)
  k_passA<<<1024, 256, 0, stream>>>(sre, sim, nullptr, buf0, U, 0, 1);
  k_passB<<<256, 512, 0, stream>>>(buf0, buf1, U, 0);
  for (int l = 1; l < 3; ++l) {
    k_passA<<<1024, 256, 0, stream>>>(nullptr, nullptr, buf1, buf0, U, l, 0);
    k_passB<<<256, 512, 0, stream>>>(buf0, buf1, U, l);
  }
  k_passA<<<1024, 256, 0, stream>>>(nullptr, nullptr, buf1, buf0, U, 3, 0);
  k_passB_ev<<<256, 512, 0, stream>>>(buf0, U, partials, 3);
  k_final<<<1, 256, 0, stream>>>(partials, out);
}